// Round 10
// baseline (1332.151 us; speedup 1.0000x reference)
//
#include <hip/hip_runtime.h>

// GroupLinearBlock: out = einsum('nhd,hdf', (rmsnorm_h(x@W) + b)/sqrt2, K)
// R10 = R9 pipeline with LDS cut to 80KB -> 2 blocks/CU (epilogue/K-loop
// overlap across resident blocks). A: 3x16KB rotating (depth-2 prefetch),
// B: 2x16KB (depth-1, L2-resident), end-of-tile vmcnt(2) (never 0 until
// tail). Flat-image staging (cvt_x_img / prep_w produce exact LDS images).
// Epilogue in two 64-row halves (per-wave y = 8KB).

typedef __attribute__((ext_vector_type(8))) __bf16 bf16x8;
typedef __attribute__((ext_vector_type(4))) float f32x4;
typedef __attribute__((ext_vector_type(8))) unsigned short ushort8;

__device__ __forceinline__ unsigned short bfbits(float f) {
  return __builtin_bit_cast(unsigned short, (__bf16)f);
}
__device__ __forceinline__ f32x4 mfma_bf16(bf16x8 a, bf16x8 b, f32x4 c) {
  return __builtin_amdgcn_mfma_f32_16x16x32_bf16(a, b, c, 0, 0, 0);
}
__device__ __forceinline__ void gl_lds16(const void* g, void* l) {
  __builtin_amdgcn_global_load_lds(
      (const __attribute__((address_space(1))) unsigned int*)g,
      (__attribute__((address_space(3))) unsigned int*)l, 16, 0, 0);
}

// ---- prep: x f32 -> A-images: ximg[rt(256)][t(32)] = 16KB block
//      [kslot(4)][row(256)][16B]; chunk(kslot,row) = bf16 x[rt*256+row][t*32+kslot*8..+8]
__global__ void cvt_x_img(const float* __restrict__ x, unsigned short* __restrict__ img) {
  const int rt = blockIdx.x, t = blockIdx.y, u = threadIdx.x;   // 256 thr
  const float* src = x + ((size_t)rt * 256 + u) * 1024 + t * 32;
  unsigned short* dst = img + ((size_t)rt * 32 + t) * 8192;     // 16KB block
  #pragma unroll
  for (int j = 0; j < 4; ++j) {
    f32x4 a = *reinterpret_cast<const f32x4*>(src + j * 8);
    f32x4 b = *reinterpret_cast<const f32x4*>(src + j * 8 + 4);
    ushort8 v;
    v[0] = bfbits(a[0]); v[1] = bfbits(a[1]); v[2] = bfbits(a[2]); v[3] = bfbits(a[3]);
    v[4] = bfbits(b[0]); v[5] = bfbits(b[1]); v[6] = bfbits(b[2]); v[7] = bfbits(b[3]);
    *reinterpret_cast<ushort8*>(dst + (size_t)(j * 256 + u) * 8) = v;
  }
}

// ---- prep: w_lin [k][n] f32 -> B-images: wb[ct(4)][t(32)][kc(4)][col(256)][8] bf16
__global__ void prep_w(const float* __restrict__ w, unsigned short* __restrict__ wb) {
  const int g = blockIdx.x * 256 + threadIdx.x;   // 0..131071 chunk id
  const int col = g & 255, kc = (g >> 8) & 3, t = (g >> 10) & 31, ct = g >> 15;
  const int k0 = t * 32 + kc * 8;
  ushort8 v;
  #pragma unroll
  for (int j = 0; j < 8; ++j) v[j] = bfbits(w[(size_t)(k0 + j) * 1024 + ct * 256 + col]);
  *reinterpret_cast<ushort8*>(wb + (size_t)g * 8) = v;
}

// ---- prep: kernel [16][d][f] f32 -> kt [16][f][d] bf16 ----
__global__ void transpose_k(const float* __restrict__ kin, unsigned short* __restrict__ kt) {
  __shared__ float tile[64][65];
  const int h = blockIdx.x;
  const int t = threadIdx.x;
  #pragma unroll
  for (int i = 0; i < 16; ++i) {
    int idx = i * 256 + t;
    tile[idx >> 6][idx & 63] = kin[(size_t)h * 4096 + idx];
  }
  __syncthreads();
  #pragma unroll
  for (int i = 0; i < 16; ++i) {
    int idx = i * 256 + t;
    kt[(size_t)h * 4096 + idx] = bfbits(tile[idx & 63][idx >> 6]);
  }
}

// ---- main: 1024 blocks x 512 threads; tile 256x256, K=1024, BK=32 ----
__global__ __launch_bounds__(512, 4)
void fused_main(const unsigned short* __restrict__ ximg,
                const float* __restrict__ nbias,
                const unsigned short* __restrict__ wb,
                const unsigned short* __restrict__ ktg_,
                float* __restrict__ out)
{
  // LDS 80KB: A bufs 3 x 16KB at [0,48K); B bufs 2 x 16KB at [48K,80K).
  // Buffer = [kslot(4)][row/col(256)][16B] (flat image copy; 2-way reads).
  // Epilogue reuses [0,64K) as per-wave y (64x64 bf16, 8KB/wave).
  __shared__ __align__(16) unsigned char smem[81920];
  const int tid = threadIdx.x;
  const int wv = tid >> 6, lane = tid & 63, l15 = lane & 15, lg = lane >> 4;
  const int l7 = l15 & 7;
  const int wr = wv >> 2, wc = wv & 3;     // wave: rows wr*128, cols wc*64
  const int bid = blockIdx.x;
  const int v = (bid & 7) * 128 + (bid >> 3);   // XCD grouping (1024 % 8 == 0)
  const int rt = v >> 2, ct = v & 3;
  const size_t row0 = (size_t)rt * 256;

  const char* aimg = (const char*)ximg + (size_t)rt * 524288 + tid * 16;
  const char* bimg = (const char*)wb + (size_t)ct * 524288 + tid * 16;

  // fragment-read byte offsets within a 16KB buffer (2-way bank aliasing, free)
  const int aBase = lg * 4096 + (wr * 128 + l15) * 16;
  const int bBase = lg * 4096 + (wc * 64 + l15) * 16;

  f32x4 acc[8][4];
  const f32x4 z4 = {0.f, 0.f, 0.f, 0.f};
  #pragma unroll
  for (int mi = 0; mi < 8; ++mi)
    #pragma unroll
    for (int ni = 0; ni < 4; ++ni) acc[mi][ni] = z4;

  auto stageA = [&](int t, int bsel) {     // 16KB flat copy (2 instr)
    unsigned char* d = smem + bsel * 16384 + tid * 16;
    const char* s = aimg + (size_t)t * 16384;
    gl_lds16(s, d);
    gl_lds16(s + 8192, d + 8192);
  };
  auto stageB = [&](int t, int bsel) {
    unsigned char* d = smem + 49152 + bsel * 16384 + tid * 16;
    const char* s = bimg + (size_t)t * 16384;
    gl_lds16(s, d);
    gl_lds16(s + 8192, d + 8192);
  };

  // ---- prologue: stage A0,B0,A1 (6 loads); wait oldest 4 (A0,B0) ----
  stageA(0, 0);
  stageB(0, 0);
  stageA(1, 1);
  asm volatile("s_waitcnt vmcnt(2)" ::: "memory");
  __builtin_amdgcn_s_barrier();

  // ---- main loop: 32 K-tiles; stage B(t+1) Ph0, A(t+2) Ph1; vmcnt(2) ----
  for (int t = 0; t < 32; ++t) {
    const int ab = t % 3, bbuf = t & 1;
    const bool stB = (t + 1 < 32), stA = (t + 2 < 32);
    const unsigned char* Ab = smem + ab * 16384;
    const unsigned char* Bb = smem + 49152 + bbuf * 16384;
    bf16x8 afr[4], bfr[4], ahr[4];

    // Ph0: reads (A m0-3 + B all); stage B(t+1); barrier; MFMA (lo)
    #pragma unroll
    for (int m = 0; m < 4; ++m)
      afr[m] = *reinterpret_cast<const bf16x8*>(Ab + aBase + m * 256);
    #pragma unroll
    for (int n = 0; n < 4; ++n)
      bfr[n] = *reinterpret_cast<const bf16x8*>(Bb + bBase + n * 256);
    if (stB) stageB(t + 1, (t + 1) & 1);
    __builtin_amdgcn_s_barrier();
    asm volatile("s_waitcnt lgkmcnt(0)" ::: "memory");
    __builtin_amdgcn_sched_barrier(0);
    __builtin_amdgcn_s_setprio(1);
    #pragma unroll
    for (int m = 0; m < 4; ++m)
      #pragma unroll
      for (int n = 0; n < 4; ++n)
        acc[m][n] = mfma_bf16(afr[m], bfr[n], acc[m][n]);
    __builtin_amdgcn_s_setprio(0);
    __builtin_amdgcn_s_barrier();

    // Ph1: reads (A m4-7); stage A(t+2); barrier; MFMA (hi)
    #pragma unroll
    for (int m = 0; m < 4; ++m)
      ahr[m] = *reinterpret_cast<const bf16x8*>(Ab + aBase + (4 + m) * 256);
    if (stA) stageA(t + 2, (t + 2) % 3);
    __builtin_amdgcn_s_barrier();
    asm volatile("s_waitcnt lgkmcnt(0)" ::: "memory");
    __builtin_amdgcn_sched_barrier(0);
    __builtin_amdgcn_s_setprio(1);
    #pragma unroll
    for (int m = 0; m < 4; ++m)
      #pragma unroll
      for (int n = 0; n < 4; ++n)
        acc[4 + m][n] = mfma_bf16(ahr[m], bfr[n], acc[4 + m][n]);
    __builtin_amdgcn_s_setprio(0);

    // end-of-tile: counted wait (A(t+2) stays in flight), barrier
    if (t < 31) {
      if (stA) asm volatile("s_waitcnt vmcnt(2)" ::: "memory");
      else     asm volatile("s_waitcnt vmcnt(0)" ::: "memory");
      __builtin_amdgcn_s_barrier();
    }
  }
  __syncthreads();   // full drain; repurpose LDS as per-wave y (8KB each)

  // ---- epilogue: two 64-row halves; RMSNorm + bias -> y LDS -> GEMM2 ----
  const int h = ct * 4 + wc;
  const unsigned short* ktp = ktg_ + (size_t)h * 4096;
  bf16x8 b2[4][2];
  #pragma unroll
  for (int ff = 0; ff < 4; ++ff)
    #pragma unroll
    for (int ks = 0; ks < 2; ++ks)
      b2[ff][ks] = *reinterpret_cast<const bf16x8*>(ktp + (ff * 16 + l15) * 64 + ks * 32 + lg * 8);

  unsigned short* yw = reinterpret_cast<unsigned short*>(smem + wv * 8192);  // 64x64 swz
  const float* bb = nbias + (row0 + wr * 128) * 1024 + (size_t)h * 64 + l15;

  #pragma unroll
  for (int hf = 0; hf < 2; ++hf) {
    #pragma unroll
    for (int mi4 = 0; mi4 < 4; ++mi4) {
      const int mi = hf * 4 + mi4;
      float ssq[4];
      #pragma unroll
      for (int r = 0; r < 4; ++r) {
        float p = 0.f;
        #pragma unroll
        for (int ni = 0; ni < 4; ++ni) { const float q = acc[mi][ni][r]; p += q * q; }
        ssq[r] = p;
      }
      #pragma unroll
      for (int s = 1; s < 16; s <<= 1)
        #pragma unroll
        for (int r = 0; r < 4; ++r) ssq[r] += __shfl_xor(ssq[r], s, 64);
      #pragma unroll
      for (int r = 0; r < 4; ++r) {
        const float rs = rsqrtf(ssq[r] * 0.015625f + 1e-6f);
        const int rl = mi4 * 16 + lg * 4 + r;            // row 0..63 within half
        const float* bp = bb + (size_t)(hf * 64 + rl) * 1024;
        #pragma unroll
        for (int ni = 0; ni < 4; ++ni) {
          const float y = (acc[mi][ni][r] * rs + bp[ni * 16]) * 0.70710678118654752f;
          const int sy = (ni * 2 + (l15 >> 3)) ^ (rl & 7);   // swizzled 16B slot
          yw[rl * 64 + sy * 8 + l7] = bfbits(y);
        }
      }
    }
    asm volatile("s_waitcnt lgkmcnt(0)" ::: "memory");   // y writes visible (own wave)

    // GEMM2 on this half: y[64][64] @ ktg_[h][f][d]
    #pragma unroll
    for (int m2 = 0; m2 < 4; ++m2) {
      f32x4 a2[4] = {z4, z4, z4, z4};
      const int row = m2 * 16 + l15;
      #pragma unroll
      for (int ks = 0; ks < 2; ++ks) {
        const int sl = ((ks * 4 + lg) ^ l7);
        bf16x8 a = *reinterpret_cast<const bf16x8*>(yw + row * 64 + sl * 8);
        #pragma unroll
        for (int ff = 0; ff < 4; ++ff) a2[ff] = mfma_bf16(a, b2[ff][ks], a2[ff]);
      }
      float* ob = out + (row0 + wr * 128 + hf * 64 + m2 * 16 + lg * 4) * 1024 + h * 64 + l15;
      #pragma unroll
      for (int ff = 0; ff < 4; ++ff)
        #pragma unroll
        for (int r = 0; r < 4; ++r)
          ob[(size_t)r * 1024 + ff * 16] = a2[ff][r];
    }
  }
}

extern "C" void kernel_launch(void* const* d_in, const int* in_sizes, int n_in,
                              void* d_out, int out_size, void* d_ws, size_t ws_size,
                              hipStream_t stream) {
  const float* x  = (const float*)d_in[0];   // [65536][1024]
  const float* nb = (const float*)d_in[1];   // [65536][16][64]
  const float* wl = (const float*)d_in[2];   // [1024][1024]
  const float* kr = (const float*)d_in[3];   // [16][64][64]
  float* out = (float*)d_out;

  unsigned short* wbp = (unsigned short*)d_ws;                      // 2 MB W images
  unsigned short* ktp = wbp + 1048576;                              // 128 KB
  unsigned short* xip = (unsigned short*)((char*)d_ws + 2228224);   // 134 MB A images

  hipLaunchKernelGGL(prep_w, dim3(512), dim3(256), 0, stream, wl, wbp);
  hipLaunchKernelGGL(transpose_k, dim3(16), dim3(256), 0, stream, kr, ktp);
  hipLaunchKernelGGL(cvt_x_img, dim3(256, 32), dim3(256), 0, stream, x, xip);
  hipLaunchKernelGGL(fused_main, dim3(1024), dim3(512), 0, stream, xip, nb, wbp, ktp, out);
}